// Round 2
// baseline (1734.390 us; speedup 1.0000x reference)
//
#include <hip/hip_runtime.h>

// Problem constants (B=1, CH=128, H=160, W=224)
#define N_PIX (160*224)          // 35840 pixels, divisible by 64 and 256
#define ORDER_CAP (396*256)      // worst-case padded order buffer (C=256)
#define CHUNK_CAP 512            // chunk_class slots (>= 140 + 256)
#define G_S2 156                 // stage-2 chunk grid: 140 + 16 classes
#define G_S3 396                 // stage-3 chunk grid: 140 + 256 classes
#define G_RG 148                 // regression chunk grid: 140 + 8 classes

__device__ __forceinline__ float lrelu(float v) { return v >= 0.f ? v : 0.01f * v; }

// ---------------------------------------------------------------------------
// Dense 128->128 layer (+leaky relu). Wave t of 4 computes outputs [32t,32t+32)
// for 64 pixels/block. W staged in LDS (64KB, 2 blocks/CU); weight reads are
// wave-uniform broadcasts (conflict-free). x streamed from global per 8-ch slab.
// In-place safe (out==in): barrier between all row reads and row writes.
// CHW=1: input layout [128,N] (x_in). CHW=0: row-major [N,128] (act).
// ---------------------------------------------------------------------------
template<int CHW>
__global__ __launch_bounds__(256) void dense128_k(const float* __restrict__ in,
    const float* __restrict__ W, const float* __restrict__ b,
    float* __restrict__ out, int N)
{
  __shared__ float Wl[128*128];   // exactly 64KB
  const int tid = threadIdx.x;
#pragma unroll
  for (int k = 0; k < 16; ++k)
    ((float4*)Wl)[k*256 + tid] = ((const float4*)W)[k*256 + tid];
  const int lane = tid & 63;
  const int t = tid >> 6;
  const int p = blockIdx.x * 64 + lane;
  float acc[32];
#pragma unroll
  for (int o = 0; o < 32; ++o) acc[o] = b[t*32 + o];
  __syncthreads();
  const float* xin = CHW ? (in + p) : (in + (size_t)p * 128);
  for (int c0 = 0; c0 < 128; c0 += 8) {
    float xs[8];
    if (CHW) {
#pragma unroll
      for (int k = 0; k < 8; ++k) xs[k] = xin[(size_t)(c0 + k) * N];
    } else {
      float4 xa = *(const float4*)(xin + c0);
      float4 xb = *(const float4*)(xin + c0 + 4);
      xs[0]=xa.x; xs[1]=xa.y; xs[2]=xa.z; xs[3]=xa.w;
      xs[4]=xb.x; xs[5]=xb.y; xs[6]=xb.z; xs[7]=xb.w;
    }
#pragma unroll
    for (int o = 0; o < 32; ++o) {
      const float* wr = &Wl[(t*32 + o)*128 + c0];
      float4 w0 = *(const float4*)wr;
      float4 w1 = *(const float4*)(wr + 4);
      acc[o] += xs[0]*w0.x + xs[1]*w0.y + xs[2]*w0.z + xs[3]*w0.w
              + xs[4]*w1.x + xs[5]*w1.y + xs[6]*w1.z + xs[7]*w1.w;
    }
  }
  __syncthreads();   // in-place safety: every thread done reading its row
  float4* orow = (float4*)(out + (size_t)p * 128 + t*32);
#pragma unroll
  for (int o4 = 0; o4 < 8; ++o4)
    orow[o4] = make_float4(lrelu(acc[4*o4+0]), lrelu(acc[4*o4+1]),
                           lrelu(acc[4*o4+2]), lrelu(acc[4*o4+3]));
}

// ---------------------------------------------------------------------------
// Mask head: x_in(128) ->32 ->16 ->1, lrelu on all. 1 px/thread.
// ---------------------------------------------------------------------------
__global__ __launch_bounds__(256) void mask_k(const float* __restrict__ xg,
    const float* __restrict__ W1, const float* __restrict__ b1,
    const float* __restrict__ W2, const float* __restrict__ b2,
    const float* __restrict__ W3, const float* __restrict__ b3,
    float* __restrict__ outm, int N)
{
  __shared__ float W1l[32*128], W2l[16*32], W3l[16];
  const int tid = threadIdx.x;
#pragma unroll
  for (int k = 0; k < 4; ++k)
    ((float4*)W1l)[k*256 + tid] = ((const float4*)W1)[k*256 + tid];
  if (tid < 128) ((float4*)W2l)[tid] = ((const float4*)W2)[tid];
  if (tid < 4)   ((float4*)W3l)[tid] = ((const float4*)W3)[tid];
  __syncthreads();
  const int p = blockIdx.x * 256 + tid;
  float a1[32];
#pragma unroll
  for (int o = 0; o < 32; ++o) a1[o] = b1[o];
  for (int c0 = 0; c0 < 128; c0 += 8) {
    float xs[8];
#pragma unroll
    for (int k = 0; k < 8; ++k) xs[k] = xg[(size_t)(c0 + k) * N + p];
#pragma unroll
    for (int o = 0; o < 32; ++o) {
      const float* wr = &W1l[o*128 + c0];
      float4 w0 = *(const float4*)wr, w1 = *(const float4*)(wr + 4);
      a1[o] += xs[0]*w0.x + xs[1]*w0.y + xs[2]*w0.z + xs[3]*w0.w
             + xs[4]*w1.x + xs[5]*w1.y + xs[6]*w1.z + xs[7]*w1.w;
    }
  }
#pragma unroll
  for (int o = 0; o < 32; ++o) a1[o] = lrelu(a1[o]);
  float a2[16];
#pragma unroll
  for (int o = 0; o < 16; ++o) a2[o] = b2[o];
#pragma unroll
  for (int i = 0; i < 32; i += 4) {
#pragma unroll
    for (int o = 0; o < 16; ++o) {
      float4 w = *(const float4*)&W2l[o*32 + i];
      a2[o] += a1[i]*w.x + a1[i+1]*w.y + a1[i+2]*w.z + a1[i+3]*w.w;
    }
  }
#pragma unroll
  for (int o = 0; o < 16; ++o) a2[o] = lrelu(a2[o]);
  float a3 = b3[0];
#pragma unroll
  for (int i = 0; i < 16; i += 4) {
    float4 w = *(const float4*)&W3l[i];
    a3 += a2[i]*w.x + a2[i+1]*w.y + a2[i+2]*w.z + a2[i+3]*w.w;
  }
  outm[p] = lrelu(a3);
}

// ---------------------------------------------------------------------------
// Stage-1 dense classifier: feat(128)->32->32->16 (no relu on last), argmax.
// Fused class histogram -> counts_next (16 classes).
// ---------------------------------------------------------------------------
__global__ __launch_bounds__(256) void stage1_k(const float* __restrict__ feat,
    const float* __restrict__ W1, const float* __restrict__ b1,   // c10 [32][128]
    const float* __restrict__ W2, const float* __restrict__ b2,   // c20 [32][32]
    const float* __restrict__ W3, const float* __restrict__ b3,   // c30 [16][32]
    int* __restrict__ inds1, int* __restrict__ counts_next, int N)
{
  __shared__ float W1l[32*128], W2l[32*32], W3l[16*32];
  __shared__ int hist[16];
  const int tid = threadIdx.x;
#pragma unroll
  for (int k = 0; k < 4; ++k)
    ((float4*)W1l)[k*256 + tid] = ((const float4*)W1)[k*256 + tid];
  ((float4*)W2l)[tid] = ((const float4*)W2)[tid];        // 1024 floats
  if (tid < 128) ((float4*)W3l)[tid] = ((const float4*)W3)[tid]; // 512 floats
  if (tid < 16) hist[tid] = 0;
  __syncthreads();
  const int p = blockIdx.x * 256 + tid;
  const float* x = feat + (size_t)p * 128;
  float a1[32];
#pragma unroll
  for (int o = 0; o < 32; ++o) a1[o] = b1[o];
  for (int c0 = 0; c0 < 128; c0 += 8) {
    float4 xa = *(const float4*)(x + c0);
    float4 xb = *(const float4*)(x + c0 + 4);
    float xs[8] = {xa.x, xa.y, xa.z, xa.w, xb.x, xb.y, xb.z, xb.w};
#pragma unroll
    for (int o = 0; o < 32; ++o) {
      const float* wr = &W1l[o*128 + c0];
      float4 w0 = *(const float4*)wr, w1 = *(const float4*)(wr + 4);
      a1[o] += xs[0]*w0.x + xs[1]*w0.y + xs[2]*w0.z + xs[3]*w0.w
             + xs[4]*w1.x + xs[5]*w1.y + xs[6]*w1.z + xs[7]*w1.w;
    }
  }
#pragma unroll
  for (int o = 0; o < 32; ++o) a1[o] = lrelu(a1[o]);
  float a2[32];
#pragma unroll
  for (int o = 0; o < 32; ++o) a2[o] = b2[o];
#pragma unroll
  for (int i = 0; i < 32; i += 4) {
#pragma unroll
    for (int o = 0; o < 32; ++o) {
      float4 w = *(const float4*)&W2l[o*32 + i];
      a2[o] += a1[i]*w.x + a1[i+1]*w.y + a1[i+2]*w.z + a1[i+3]*w.w;
    }
  }
#pragma unroll
  for (int o = 0; o < 32; ++o) a2[o] = lrelu(a2[o]);
  float lg[16];
#pragma unroll
  for (int o = 0; o < 16; ++o) lg[o] = b3[o];
#pragma unroll
  for (int i = 0; i < 32; i += 4) {
#pragma unroll
    for (int o = 0; o < 16; ++o) {
      float4 w = *(const float4*)&W3l[o*32 + i];
      lg[o] += a2[i]*w.x + a2[i+1]*w.y + a2[i+2]*w.z + a2[i+3]*w.w;
    }
  }
  float bv = lg[0]; int bi = 0;
#pragma unroll
  for (int o = 1; o < 16; ++o) if (lg[o] > bv) { bv = lg[o]; bi = o; }
  inds1[p] = bi;
  atomicAdd(&hist[bi], 1);
  __syncthreads();
  if (tid < 16 && hist[tid] > 0) atomicAdd(&counts_next[tid], hist[tid]);
}

// ---------------------------------------------------------------------------
// CondMul stage (2 or 3): 128->32->32->32, argmax, ind' = clip(cls*16+i-8,0,hi)
// Class-binned: each block = one class chunk; class weights staged in LDS.
// Validity by bound check (no order-buffer init needed). Fused histogram of
// (out_ind >> next_shift) -> counts_next.
// ---------------------------------------------------------------------------
__global__ __launch_bounds__(256) void stage23_k(const float* __restrict__ act,
    const float* __restrict__ W1g, const float* __restrict__ b1g,  // [C,128,32]
    const float* __restrict__ W2g, const float* __restrict__ b2g,  // [C,32,32]
    const float* __restrict__ W3g, const float* __restrict__ b3g,  // [C,32,32]
    const int* __restrict__ chunk_class, const int* __restrict__ order,
    const int* __restrict__ offs_this, const int* __restrict__ cnts_this,
    int* __restrict__ out_ind, int hi,
    int* __restrict__ counts_next, int next_shift, int next_nc)
{
  const int cls = chunk_class[blockIdx.x];
  if (cls < 0) return;                      // block-uniform: no barriers skipped
  __shared__ float W1l[128*32], W2l[32*32], W3l[32*32];
  __shared__ float b1l[32], b2l[32], b3l[32];
  __shared__ int hist[256];
  const int tid = threadIdx.x;
  const float* W1 = W1g + (size_t)cls * 4096;
  const float* W2 = W2g + (size_t)cls * 1024;
  const float* W3 = W3g + (size_t)cls * 1024;
#pragma unroll
  for (int k = 0; k < 4; ++k)
    ((float4*)W1l)[k*256 + tid] = ((const float4*)W1)[k*256 + tid];
  ((float4*)W2l)[tid] = ((const float4*)W2)[tid];
  ((float4*)W3l)[tid] = ((const float4*)W3)[tid];
  if (tid < 32) {
    b1l[tid] = b1g[cls*32 + tid];
    b2l[tid] = b2g[cls*32 + tid];
    b3l[tid] = b3g[cls*32 + tid];
  }
  hist[tid] = 0;
  const int slot = blockIdx.x * 256 + tid;
  const int end = offs_this[cls] + cnts_this[cls];
  __syncthreads();
  const bool valid = slot < end;
  if (valid) {
    const int p = order[slot];
    const float* x = act + (size_t)p * 128;
    float a1[32];
#pragma unroll
    for (int o = 0; o < 32; ++o) a1[o] = b1l[o];
    for (int i0 = 0; i0 < 128; i0 += 8) {
      float4 xa = *(const float4*)(x + i0);
      float4 xb = *(const float4*)(x + i0 + 4);
      float xs[8] = {xa.x, xa.y, xa.z, xa.w, xb.x, xb.y, xb.z, xb.w};
#pragma unroll
      for (int i = 0; i < 8; ++i) {
#pragma unroll
        for (int o4 = 0; o4 < 8; ++o4) {
          float4 w = *(const float4*)&W1l[(i0 + i)*32 + o4*4];
          a1[o4*4+0] += xs[i]*w.x; a1[o4*4+1] += xs[i]*w.y;
          a1[o4*4+2] += xs[i]*w.z; a1[o4*4+3] += xs[i]*w.w;
        }
      }
    }
#pragma unroll
    for (int o = 0; o < 32; ++o) a1[o] = lrelu(a1[o]);
    float a2[32];
#pragma unroll
    for (int o = 0; o < 32; ++o) a2[o] = b2l[o];
#pragma unroll
    for (int i = 0; i < 32; ++i) {
#pragma unroll
      for (int o4 = 0; o4 < 8; ++o4) {
        float4 w = *(const float4*)&W2l[i*32 + o4*4];
        a2[o4*4+0] += a1[i]*w.x; a2[o4*4+1] += a1[i]*w.y;
        a2[o4*4+2] += a1[i]*w.z; a2[o4*4+3] += a1[i]*w.w;
      }
    }
#pragma unroll
    for (int o = 0; o < 32; ++o) a2[o] = lrelu(a2[o]);
    float a3[32];
#pragma unroll
    for (int o = 0; o < 32; ++o) a3[o] = b3l[o];
#pragma unroll
    for (int i = 0; i < 32; ++i) {
#pragma unroll
      for (int o4 = 0; o4 < 8; ++o4) {
        float4 w = *(const float4*)&W3l[i*32 + o4*4];
        a3[o4*4+0] += a2[i]*w.x; a3[o4*4+1] += a2[i]*w.y;
        a3[o4*4+2] += a2[i]*w.z; a3[o4*4+3] += a2[i]*w.w;
      }
    }
    float bv = a3[0]; int bi = 0;
#pragma unroll
    for (int o = 1; o < 32; ++o) if (a3[o] > bv) { bv = a3[o]; bi = o; }
    int v = cls*16 + bi - 8;
    v = v < 0 ? 0 : (v > hi ? hi : v);
    out_ind[p] = v;
    atomicAdd(&hist[v >> next_shift], 1);
  }
  __syncthreads();
  if (tid < next_nc && hist[tid] > 0) atomicAdd(&counts_next[tid], hist[tid]);
}

// ---------------------------------------------------------------------------
// Regression: t = lrelu(cmul(xr, super, r2)); r = cmul(t, inds123, r3);
// out = (inds123 + r)/4096. Binned by super-class (8); r3 gathered per-pixel.
// ---------------------------------------------------------------------------
__global__ __launch_bounds__(256) void reg_k(const float* __restrict__ act,
    const float* __restrict__ W1g, const float* __restrict__ b1g,  // r2 [8,128,32]
    const float* __restrict__ r3W, const float* __restrict__ r3b,  // [4096,32],[4096]
    const int* __restrict__ chunk_class, const int* __restrict__ order,
    const int* __restrict__ offs_this, const int* __restrict__ cnts_this,
    const int* __restrict__ inds123, float* __restrict__ outr)
{
  const int cls = chunk_class[blockIdx.x];
  if (cls < 0) return;
  __shared__ float W1l[128*32], b1l[32];
  const int tid = threadIdx.x;
  const float* W1 = W1g + (size_t)cls * 4096;
#pragma unroll
  for (int k = 0; k < 4; ++k)
    ((float4*)W1l)[k*256 + tid] = ((const float4*)W1)[k*256 + tid];
  if (tid < 32) b1l[tid] = b1g[cls*32 + tid];
  const int slot = blockIdx.x * 256 + tid;
  const int end = offs_this[cls] + cnts_this[cls];
  __syncthreads();
  if (slot >= end) return;                 // after last barrier: safe
  const int p = order[slot];
  const float* x = act + (size_t)p * 128;
  float a1[32];
#pragma unroll
  for (int o = 0; o < 32; ++o) a1[o] = b1l[o];
  for (int i0 = 0; i0 < 128; i0 += 8) {
    float4 xa = *(const float4*)(x + i0);
    float4 xb = *(const float4*)(x + i0 + 4);
    float xs[8] = {xa.x, xa.y, xa.z, xa.w, xb.x, xb.y, xb.z, xb.w};
#pragma unroll
    for (int i = 0; i < 8; ++i) {
#pragma unroll
      for (int o4 = 0; o4 < 8; ++o4) {
        float4 w = *(const float4*)&W1l[(i0 + i)*32 + o4*4];
        a1[o4*4+0] += xs[i]*w.x; a1[o4*4+1] += xs[i]*w.y;
        a1[o4*4+2] += xs[i]*w.z; a1[o4*4+3] += xs[i]*w.w;
      }
    }
  }
#pragma unroll
  for (int o = 0; o < 32; ++o) a1[o] = lrelu(a1[o]);
  const int ind = inds123[p];
  const float4* rw = (const float4*)(r3W + (size_t)ind * 32);
  float r = r3b[ind];
#pragma unroll
  for (int k = 0; k < 8; ++k) {
    float4 w = rw[k];
    r += a1[4*k+0]*w.x + a1[4*k+1]*w.y + a1[4*k+2]*w.z + a1[4*k+3]*w.w;
  }
  outr[p] = ((float)ind + r) * (1.0f / 4096.0f);
}

// ---------------------------------------------------------------------------
// Binning support: one upfront zeroing kernel; per-stage LDS-scan (1 block);
// per-stage scatter. No order-buffer init (validity via offsets+counts bound).
// ---------------------------------------------------------------------------
__global__ void init_counts_k(int* c1, int* c2, int* c3)
{
  const int tid = threadIdx.x;
  c1[tid] = 0; c2[tid] = 0; c3[tid] = 0;
}

// Single block of 256. Exclusive padded scan over C class counts; writes
// offsets, zeroes cursors, fills chunk_class[0..fillTo) (class id or -1).
__global__ void bin_scan_k(const int* __restrict__ counts, int* __restrict__ offsets,
                           int* __restrict__ cursors, int* __restrict__ chunk_class,
                           int C, int fillTo)
{
  __shared__ int cl[256], ol[256];
  __shared__ int totChunks;
  const int tid = threadIdx.x;
  if (tid < C) cl[tid] = counts[tid];
  __syncthreads();
  if (tid == 0) {
    int off = 0;
    for (int c = 0; c < C; ++c) {
      ol[c] = off;
      off += ((cl[c] + 255) >> 8) << 8;
    }
    totChunks = off >> 8;
  }
  __syncthreads();
  if (tid < C) {
    offsets[tid] = ol[tid];
    cursors[tid] = 0;
    const int start = ol[tid] >> 8;
    const int nch = (cl[tid] + 255) >> 8;
    for (int k = 0; k < nch; ++k) chunk_class[start + k] = tid;
  }
  for (int k = totChunks + tid; k < fillTo; k += 256) chunk_class[k] = -1;
}

__global__ void bin_scatter_k(const int* __restrict__ ind, const int* __restrict__ offsets,
                              int* cursors, int* order, int N, int shift)
{
  int p = blockIdx.x * blockDim.x + threadIdx.x;
  if (p < N) {
    int c = ind[p] >> shift;
    int pos = offsets[c] + atomicAdd(&cursors[c], 1);
    order[pos] = p;
  }
}

// ---------------------------------------------------------------------------
extern "C" void kernel_launch(void* const* d_in, const int* in_sizes, int n_in,
                              void* d_out, int out_size, void* d_ws, size_t ws_size,
                              hipStream_t stream)
{
  const int N = N_PIX;
  const float* x_in  = (const float*)d_in[0];
  const float* bb1_w = (const float*)d_in[1];  const float* bb1_b = (const float*)d_in[2];
  const float* bb2_w = (const float*)d_in[3];  const float* bb2_b = (const float*)d_in[4];
  const float* bb3_w = (const float*)d_in[5];  const float* bb3_b = (const float*)d_in[6];
  const float* msk1_w= (const float*)d_in[7];  const float* msk1_b= (const float*)d_in[8];
  const float* msk2_w= (const float*)d_in[9];  const float* msk2_b= (const float*)d_in[10];
  const float* msk3_w= (const float*)d_in[11]; const float* msk3_b= (const float*)d_in[12];
  const float* c10_w = (const float*)d_in[13]; const float* c10_b = (const float*)d_in[14];
  const float* c20_w = (const float*)d_in[15]; const float* c20_b = (const float*)d_in[16];
  const float* c30_w = (const float*)d_in[17]; const float* c30_b = (const float*)d_in[18];
  const float* c11_W = (const float*)d_in[19]; const float* c11_b = (const float*)d_in[20];
  const float* c21_W = (const float*)d_in[21]; const float* c21_b = (const float*)d_in[22];
  const float* c31_W = (const float*)d_in[23]; const float* c31_b = (const float*)d_in[24];
  const float* c12_W = (const float*)d_in[25]; const float* c12_b = (const float*)d_in[26];
  const float* c22_W = (const float*)d_in[27]; const float* c22_b = (const float*)d_in[28];
  const float* c32_W = (const float*)d_in[29]; const float* c32_b = (const float*)d_in[30];
  const float* r1_w  = (const float*)d_in[31]; const float* r1_b  = (const float*)d_in[32];
  const float* r2_W  = (const float*)d_in[33]; const float* r2_b  = (const float*)d_in[34];
  const float* r3_W  = (const float*)d_in[35]; const float* r3_b  = (const float*)d_in[36];

  // ws layout (fp32/i32), ~19.6 MB total
  float* act     = (float*)d_ws;                    // N*128
  int*   inds1   = (int*)(act + (size_t)N * 128);   // N
  int*   inds12  = inds1 + N;                       // N
  int*   inds123 = inds12 + N;                      // N
  int*   counts1 = inds123 + N;                     // 256 each (only 16/256/8 used)
  int*   counts2 = counts1 + 256;
  int*   counts3 = counts2 + 256;
  int*   offs1   = counts3 + 256;
  int*   offs2   = offs1 + 256;
  int*   offs3   = offs2 + 256;
  int*   curs1   = offs3 + 256;
  int*   curs2   = curs1 + 256;
  int*   curs3   = curs2 + 256;
  int*   chunk_cls = curs3 + 256;                   // CHUNK_CAP (shared, sequential)
  int*   order     = chunk_cls + CHUNK_CAP;         // ORDER_CAP (shared, sequential)

  float* out_reg  = (float*)d_out;       // [N] regression output (return slot 0)
  float* out_mask = out_reg + N;         // [N] mask output (return slot 1)

  const dim3 B(256);
  const int gPix64  = N / 64;    // 560
  const int gPix256 = N / 256;   // 140

  init_counts_k<<<1, B, 0, stream>>>(counts1, counts2, counts3);

  // --- backbone (in-place act) ---
  dense128_k<1><<<gPix64, B, 0, stream>>>(x_in, bb1_w, bb1_b, act, N);
  dense128_k<0><<<gPix64, B, 0, stream>>>(act,  bb2_w, bb2_b, act, N);
  dense128_k<0><<<gPix64, B, 0, stream>>>(act,  bb3_w, bb3_b, act, N);  // act = feat

  // --- mask head (x_in only) ---
  mask_k<<<gPix256, B, 0, stream>>>(x_in, msk1_w, msk1_b, msk2_w, msk2_b,
                                    msk3_w, msk3_b, out_mask, N);

  // --- stage 1: dense classifier -> inds1 (+fused 16-class histogram) ---
  stage1_k<<<gPix256, B, 0, stream>>>(act, c10_w, c10_b, c20_w, c20_b,
                                      c30_w, c30_b, inds1, counts1, N);

  // --- stage 2: bin by inds1 (16 cls), CondMul -> inds12 (+256-cls hist) ---
  bin_scan_k<<<1, B, 0, stream>>>(counts1, offs1, curs1, chunk_cls, 16, G_S2);
  bin_scatter_k<<<gPix256, B, 0, stream>>>(inds1, offs1, curs1, order, N, 0);
  stage23_k<<<G_S2, B, 0, stream>>>(act, c11_W, c11_b, c21_W, c21_b, c31_W, c31_b,
                                    chunk_cls, order, offs1, counts1,
                                    inds12, 255, counts2, 0, 256);

  // --- stage 3: bin by inds12 (256 cls), CondMul -> inds123 (+8-superclass hist) ---
  bin_scan_k<<<1, B, 0, stream>>>(counts2, offs2, curs2, chunk_cls, 256, G_S3);
  bin_scatter_k<<<gPix256, B, 0, stream>>>(inds12, offs2, curs2, order, N, 0);
  stage23_k<<<G_S3, B, 0, stream>>>(act, c12_W, c12_b, c22_W, c22_b, c32_W, c32_b,
                                    chunk_cls, order, offs2, counts2,
                                    inds123, 4095, counts3, 9, 8);

  // --- regression input: xr = lrelu(r1 @ x_in), overwrites act (feat dead) ---
  dense128_k<1><<<gPix64, B, 0, stream>>>(x_in, r1_w, r1_b, act, N);

  // --- bin by super-class (inds123 >> 9, 8 cls), r2 + gathered r3 -> out ---
  bin_scan_k<<<1, B, 0, stream>>>(counts3, offs3, curs3, chunk_cls, 8, G_RG);
  bin_scatter_k<<<gPix256, B, 0, stream>>>(inds123, offs3, curs3, order, N, 9);
  reg_k<<<G_RG, B, 0, stream>>>(act, r2_W, r2_b, r3_W, r3_b,
                                chunk_cls, order, offs3, counts3, inds123, out_reg);
}

// Round 3
// 526.342 us; speedup vs baseline: 3.2952x; 3.2952x over previous
//
#include <hip/hip_runtime.h>

// Problem constants (B=1, CH=128, H=160, W=224)
#define N_PIX (160*224)          // 35840 pixels
#define ORDER_CAP (396*256)      // worst-case padded order buffer (C=256)
#define CHUNK_CAP 512            // chunk_class slots (>= 140 + 256)
#define G_S2 156                 // stage-2 chunk grid: 140 + 16 classes
#define G_S3 396                 // stage-3 chunk grid: 140 + 256 classes
#define G_RG 148                 // regression chunk grid: 140 + 8 classes
#define NB   70                  // binning blocks; 70*512 == 35840
#define BCHUNK 512               // pixels per binning block (2 rounds of 256)

__device__ __forceinline__ float lrelu(float v) { return v >= 0.f ? v : 0.01f * v; }

// ---------------------------------------------------------------------------
// Dense 128->128 layer (+leaky relu). Wave t of 4 computes outputs [32t,32t+32)
// for 64 pixels/block. W staged in LDS (64KB, 2 blocks/CU); weight reads are
// wave-uniform broadcasts (conflict-free). In-place safe (barrier before write).
// CHW=1: input layout [128,N] (x_in). CHW=0: row-major [N,128] (act).
// ---------------------------------------------------------------------------
template<int CHW>
__global__ __launch_bounds__(256) void dense128_k(const float* __restrict__ in,
    const float* __restrict__ W, const float* __restrict__ b,
    float* __restrict__ out, int N)
{
  __shared__ float Wl[128*128];   // exactly 64KB
  const int tid = threadIdx.x;
#pragma unroll
  for (int k = 0; k < 16; ++k)
    ((float4*)Wl)[k*256 + tid] = ((const float4*)W)[k*256 + tid];
  const int lane = tid & 63;
  const int t = tid >> 6;
  const int p = blockIdx.x * 64 + lane;
  float acc[32];
#pragma unroll
  for (int o = 0; o < 32; ++o) acc[o] = b[t*32 + o];
  __syncthreads();
  const float* xin = CHW ? (in + p) : (in + (size_t)p * 128);
  for (int c0 = 0; c0 < 128; c0 += 8) {
    float xs[8];
    if (CHW) {
#pragma unroll
      for (int k = 0; k < 8; ++k) xs[k] = xin[(size_t)(c0 + k) * N];
    } else {
      float4 xa = *(const float4*)(xin + c0);
      float4 xb = *(const float4*)(xin + c0 + 4);
      xs[0]=xa.x; xs[1]=xa.y; xs[2]=xa.z; xs[3]=xa.w;
      xs[4]=xb.x; xs[5]=xb.y; xs[6]=xb.z; xs[7]=xb.w;
    }
#pragma unroll
    for (int o = 0; o < 32; ++o) {
      const float* wr = &Wl[(t*32 + o)*128 + c0];
      float4 w0 = *(const float4*)wr;
      float4 w1 = *(const float4*)(wr + 4);
      acc[o] += xs[0]*w0.x + xs[1]*w0.y + xs[2]*w0.z + xs[3]*w0.w
              + xs[4]*w1.x + xs[5]*w1.y + xs[6]*w1.z + xs[7]*w1.w;
    }
  }
  __syncthreads();   // in-place safety: every thread done reading its row
  float4* orow = (float4*)(out + (size_t)p * 128 + t*32);
#pragma unroll
  for (int o4 = 0; o4 < 8; ++o4)
    orow[o4] = make_float4(lrelu(acc[4*o4+0]), lrelu(acc[4*o4+1]),
                           lrelu(acc[4*o4+2]), lrelu(acc[4*o4+3]));
}

// ---------------------------------------------------------------------------
// Mask head: x_in(128) ->32 ->16 ->1, lrelu on all. 1 px/thread.
// ---------------------------------------------------------------------------
__global__ __launch_bounds__(256) void mask_k(const float* __restrict__ xg,
    const float* __restrict__ W1, const float* __restrict__ b1,
    const float* __restrict__ W2, const float* __restrict__ b2,
    const float* __restrict__ W3, const float* __restrict__ b3,
    float* __restrict__ outm, int N)
{
  __shared__ float W1l[32*128], W2l[16*32], W3l[16];
  const int tid = threadIdx.x;
#pragma unroll
  for (int k = 0; k < 4; ++k)
    ((float4*)W1l)[k*256 + tid] = ((const float4*)W1)[k*256 + tid];
  if (tid < 128) ((float4*)W2l)[tid] = ((const float4*)W2)[tid];
  if (tid < 4)   ((float4*)W3l)[tid] = ((const float4*)W3)[tid];
  __syncthreads();
  const int p = blockIdx.x * 256 + tid;
  float a1[32];
#pragma unroll
  for (int o = 0; o < 32; ++o) a1[o] = b1[o];
  for (int c0 = 0; c0 < 128; c0 += 8) {
    float xs[8];
#pragma unroll
    for (int k = 0; k < 8; ++k) xs[k] = xg[(size_t)(c0 + k) * N + p];
#pragma unroll
    for (int o = 0; o < 32; ++o) {
      const float* wr = &W1l[o*128 + c0];
      float4 w0 = *(const float4*)wr, w1 = *(const float4*)(wr + 4);
      a1[o] += xs[0]*w0.x + xs[1]*w0.y + xs[2]*w0.z + xs[3]*w0.w
             + xs[4]*w1.x + xs[5]*w1.y + xs[6]*w1.z + xs[7]*w1.w;
    }
  }
#pragma unroll
  for (int o = 0; o < 32; ++o) a1[o] = lrelu(a1[o]);
  float a2[16];
#pragma unroll
  for (int o = 0; o < 16; ++o) a2[o] = b2[o];
#pragma unroll
  for (int i = 0; i < 32; i += 4) {
#pragma unroll
    for (int o = 0; o < 16; ++o) {
      float4 w = *(const float4*)&W2l[o*32 + i];
      a2[o] += a1[i]*w.x + a1[i+1]*w.y + a1[i+2]*w.z + a1[i+3]*w.w;
    }
  }
#pragma unroll
  for (int o = 0; o < 16; ++o) a2[o] = lrelu(a2[o]);
  float a3 = b3[0];
#pragma unroll
  for (int i = 0; i < 16; i += 4) {
    float4 w = *(const float4*)&W3l[i];
    a3 += a2[i]*w.x + a2[i+1]*w.y + a2[i+2]*w.z + a2[i+3]*w.w;
  }
  outm[p] = lrelu(a3);
}

// ---------------------------------------------------------------------------
// Stage-1 dense classifier: feat(128)->32->32->16 (no relu on last), argmax.
// Pure compute (histogram moved to hist_k).
// ---------------------------------------------------------------------------
__global__ __launch_bounds__(256) void stage1_k(const float* __restrict__ feat,
    const float* __restrict__ W1, const float* __restrict__ b1,   // c10 [32][128]
    const float* __restrict__ W2, const float* __restrict__ b2,   // c20 [32][32]
    const float* __restrict__ W3, const float* __restrict__ b3,   // c30 [16][32]
    int* __restrict__ inds1, int N)
{
  __shared__ float W1l[32*128], W2l[32*32], W3l[16*32];
  const int tid = threadIdx.x;
#pragma unroll
  for (int k = 0; k < 4; ++k)
    ((float4*)W1l)[k*256 + tid] = ((const float4*)W1)[k*256 + tid];
  ((float4*)W2l)[tid] = ((const float4*)W2)[tid];        // 1024 floats
  if (tid < 128) ((float4*)W3l)[tid] = ((const float4*)W3)[tid]; // 512 floats
  __syncthreads();
  const int p = blockIdx.x * 256 + tid;
  const float* x = feat + (size_t)p * 128;
  float a1[32];
#pragma unroll
  for (int o = 0; o < 32; ++o) a1[o] = b1[o];
  for (int c0 = 0; c0 < 128; c0 += 8) {
    float4 xa = *(const float4*)(x + c0);
    float4 xb = *(const float4*)(x + c0 + 4);
    float xs[8] = {xa.x, xa.y, xa.z, xa.w, xb.x, xb.y, xb.z, xb.w};
#pragma unroll
    for (int o = 0; o < 32; ++o) {
      const float* wr = &W1l[o*128 + c0];
      float4 w0 = *(const float4*)wr, w1 = *(const float4*)(wr + 4);
      a1[o] += xs[0]*w0.x + xs[1]*w0.y + xs[2]*w0.z + xs[3]*w0.w
             + xs[4]*w1.x + xs[5]*w1.y + xs[6]*w1.z + xs[7]*w1.w;
    }
  }
#pragma unroll
  for (int o = 0; o < 32; ++o) a1[o] = lrelu(a1[o]);
  float a2[32];
#pragma unroll
  for (int o = 0; o < 32; ++o) a2[o] = b2[o];
#pragma unroll
  for (int i = 0; i < 32; i += 4) {
#pragma unroll
    for (int o = 0; o < 32; ++o) {
      float4 w = *(const float4*)&W2l[o*32 + i];
      a2[o] += a1[i]*w.x + a1[i+1]*w.y + a1[i+2]*w.z + a1[i+3]*w.w;
    }
  }
#pragma unroll
  for (int o = 0; o < 32; ++o) a2[o] = lrelu(a2[o]);
  float lg[16];
#pragma unroll
  for (int o = 0; o < 16; ++o) lg[o] = b3[o];
#pragma unroll
  for (int i = 0; i < 32; i += 4) {
#pragma unroll
    for (int o = 0; o < 16; ++o) {
      float4 w = *(const float4*)&W3l[o*32 + i];
      lg[o] += a2[i]*w.x + a2[i+1]*w.y + a2[i+2]*w.z + a2[i+3]*w.w;
    }
  }
  float bv = lg[0]; int bi = 0;
#pragma unroll
  for (int o = 1; o < 16; ++o) if (lg[o] > bv) { bv = lg[o]; bi = o; }
  inds1[p] = bi;
}

// ---------------------------------------------------------------------------
// CondMul stage (2 or 3): 128->32->32->32, argmax, ind' = clip(cls*16+i-8,0,hi)
// Class-binned: each block = one class chunk; class weights staged in LDS.
// Validity via offsets+counts bound (no order-buffer init, no atomics).
// ---------------------------------------------------------------------------
__global__ __launch_bounds__(256) void stage23_k(const float* __restrict__ act,
    const float* __restrict__ W1g, const float* __restrict__ b1g,  // [C,128,32]
    const float* __restrict__ W2g, const float* __restrict__ b2g,  // [C,32,32]
    const float* __restrict__ W3g, const float* __restrict__ b3g,  // [C,32,32]
    const int* __restrict__ chunk_class, const int* __restrict__ order,
    const int* __restrict__ offs_this, const int* __restrict__ cnts_this,
    int* __restrict__ out_ind, int hi)
{
  const int cls = chunk_class[blockIdx.x];
  if (cls < 0) return;                      // block-uniform
  __shared__ float W1l[128*32], W2l[32*32], W3l[32*32];
  __shared__ float b1l[32], b2l[32], b3l[32];
  const int tid = threadIdx.x;
  const float* W1 = W1g + (size_t)cls * 4096;
  const float* W2 = W2g + (size_t)cls * 1024;
  const float* W3 = W3g + (size_t)cls * 1024;
#pragma unroll
  for (int k = 0; k < 4; ++k)
    ((float4*)W1l)[k*256 + tid] = ((const float4*)W1)[k*256 + tid];
  ((float4*)W2l)[tid] = ((const float4*)W2)[tid];
  ((float4*)W3l)[tid] = ((const float4*)W3)[tid];
  if (tid < 32) {
    b1l[tid] = b1g[cls*32 + tid];
    b2l[tid] = b2g[cls*32 + tid];
    b3l[tid] = b3g[cls*32 + tid];
  }
  const int slot = blockIdx.x * 256 + tid;
  const int end = offs_this[cls] + cnts_this[cls];
  __syncthreads();
  if (slot >= end) return;                  // after last barrier: safe
  const int p = order[slot];
  const float* x = act + (size_t)p * 128;
  float a1[32];
#pragma unroll
  for (int o = 0; o < 32; ++o) a1[o] = b1l[o];
  for (int i0 = 0; i0 < 128; i0 += 8) {
    float4 xa = *(const float4*)(x + i0);
    float4 xb = *(const float4*)(x + i0 + 4);
    float xs[8] = {xa.x, xa.y, xa.z, xa.w, xb.x, xb.y, xb.z, xb.w};
#pragma unroll
    for (int i = 0; i < 8; ++i) {
#pragma unroll
      for (int o4 = 0; o4 < 8; ++o4) {
        float4 w = *(const float4*)&W1l[(i0 + i)*32 + o4*4];
        a1[o4*4+0] += xs[i]*w.x; a1[o4*4+1] += xs[i]*w.y;
        a1[o4*4+2] += xs[i]*w.z; a1[o4*4+3] += xs[i]*w.w;
      }
    }
  }
#pragma unroll
  for (int o = 0; o < 32; ++o) a1[o] = lrelu(a1[o]);
  float a2[32];
#pragma unroll
  for (int o = 0; o < 32; ++o) a2[o] = b2l[o];
#pragma unroll
  for (int i = 0; i < 32; ++i) {
#pragma unroll
    for (int o4 = 0; o4 < 8; ++o4) {
      float4 w = *(const float4*)&W2l[i*32 + o4*4];
      a2[o4*4+0] += a1[i]*w.x; a2[o4*4+1] += a1[i]*w.y;
      a2[o4*4+2] += a1[i]*w.z; a2[o4*4+3] += a1[i]*w.w;
    }
  }
#pragma unroll
  for (int o = 0; o < 32; ++o) a2[o] = lrelu(a2[o]);
  float a3[32];
#pragma unroll
  for (int o = 0; o < 32; ++o) a3[o] = b3l[o];
#pragma unroll
  for (int i = 0; i < 32; ++i) {
#pragma unroll
    for (int o4 = 0; o4 < 8; ++o4) {
      float4 w = *(const float4*)&W3l[i*32 + o4*4];
      a3[o4*4+0] += a2[i]*w.x; a3[o4*4+1] += a2[i]*w.y;
      a3[o4*4+2] += a2[i]*w.z; a3[o4*4+3] += a2[i]*w.w;
    }
  }
  float bv = a3[0]; int bi = 0;
#pragma unroll
  for (int o = 1; o < 32; ++o) if (a3[o] > bv) { bv = a3[o]; bi = o; }
  int v = cls*16 + bi - 8;
  v = v < 0 ? 0 : (v > hi ? hi : v);
  out_ind[p] = v;
}

// ---------------------------------------------------------------------------
// Regression: t = lrelu(cmul(xr, super, r2)); r = cmul(t, inds123, r3);
// out = (inds123 + r)/4096. Binned by super-class (8); r3 gathered per-pixel.
// ---------------------------------------------------------------------------
__global__ __launch_bounds__(256) void reg_k(const float* __restrict__ act,
    const float* __restrict__ W1g, const float* __restrict__ b1g,  // r2 [8,128,32]
    const float* __restrict__ r3W, const float* __restrict__ r3b,  // [4096,32],[4096]
    const int* __restrict__ chunk_class, const int* __restrict__ order,
    const int* __restrict__ offs_this, const int* __restrict__ cnts_this,
    const int* __restrict__ inds123, float* __restrict__ outr)
{
  const int cls = chunk_class[blockIdx.x];
  if (cls < 0) return;
  __shared__ float W1l[128*32], b1l[32];
  const int tid = threadIdx.x;
  const float* W1 = W1g + (size_t)cls * 4096;
#pragma unroll
  for (int k = 0; k < 4; ++k)
    ((float4*)W1l)[k*256 + tid] = ((const float4*)W1)[k*256 + tid];
  if (tid < 32) b1l[tid] = b1g[cls*32 + tid];
  const int slot = blockIdx.x * 256 + tid;
  const int end = offs_this[cls] + cnts_this[cls];
  __syncthreads();
  if (slot >= end) return;
  const int p = order[slot];
  const float* x = act + (size_t)p * 128;
  float a1[32];
#pragma unroll
  for (int o = 0; o < 32; ++o) a1[o] = b1l[o];
  for (int i0 = 0; i0 < 128; i0 += 8) {
    float4 xa = *(const float4*)(x + i0);
    float4 xb = *(const float4*)(x + i0 + 4);
    float xs[8] = {xa.x, xa.y, xa.z, xa.w, xb.x, xb.y, xb.z, xb.w};
#pragma unroll
    for (int i = 0; i < 8; ++i) {
#pragma unroll
      for (int o4 = 0; o4 < 8; ++o4) {
        float4 w = *(const float4*)&W1l[(i0 + i)*32 + o4*4];
        a1[o4*4+0] += xs[i]*w.x; a1[o4*4+1] += xs[i]*w.y;
        a1[o4*4+2] += xs[i]*w.z; a1[o4*4+3] += xs[i]*w.w;
      }
    }
  }
#pragma unroll
  for (int o = 0; o < 32; ++o) a1[o] = lrelu(a1[o]);
  const int ind = inds123[p];
  const float4* rw = (const float4*)(r3W + (size_t)ind * 32);
  float r = r3b[ind];
#pragma unroll
  for (int k = 0; k < 8; ++k) {
    float4 w = rw[k];
    r += a1[4*k+0]*w.x + a1[4*k+1]*w.y + a1[4*k+2]*w.z + a1[4*k+3]*w.w;
  }
  outr[p] = ((float)ind + r) * (1.0f / 4096.0f);
}

// ---------------------------------------------------------------------------
// Deterministic, atomic-free binning (per stage boundary):
//   hist_k:    per-block LDS histogram of ind>>shift -> blkcnt[NB][C] (stores)
//   scan_k:    1 block: totals, padded offsets, chunk_class, per-block bases
//   scatter_k: rank within (block,class) via LDS atomics; place into order[]
// Only LDS atomics anywhere -> no same-cacheline global RMW chains.
// ---------------------------------------------------------------------------
__global__ __launch_bounds__(256) void hist_k(const int* __restrict__ ind,
    int* __restrict__ blkcnt, int shift, int C)
{
  __shared__ int h[256];
  const int tid = threadIdx.x, b = blockIdx.x;
  h[tid] = 0;
  __syncthreads();
  const int base = b * BCHUNK;
  atomicAdd(&h[ind[base + tid] >> shift], 1);
  atomicAdd(&h[ind[base + 256 + tid] >> shift], 1);
  __syncthreads();
  if (tid < C) blkcnt[b * C + tid] = h[tid];
}

__global__ __launch_bounds__(256) void scan_k(const int* __restrict__ blkcnt,
    int* __restrict__ blkbase, int* __restrict__ offsets, int* __restrict__ counts,
    int* __restrict__ chunk_class, int C, int fillTo)
{
  __shared__ int cl[256], ol[256];
  __shared__ int totChunks;
  const int tid = threadIdx.x;
  if (tid < C) {
    int s = 0;
    for (int b = 0; b < NB; ++b) s += blkcnt[b * C + tid];
    cl[tid] = s;
  }
  __syncthreads();
  if (tid == 0) {
    int off = 0;
    for (int c = 0; c < C; ++c) {
      ol[c] = off;
      off += ((cl[c] + 255) >> 8) << 8;
    }
    totChunks = off >> 8;
  }
  __syncthreads();
  if (tid < C) {
    offsets[tid] = ol[tid];
    counts[tid]  = cl[tid];
    int acc = ol[tid];
    for (int b = 0; b < NB; ++b) {
      int v = blkcnt[b * C + tid];
      blkbase[b * C + tid] = acc;
      acc += v;
    }
    const int start = ol[tid] >> 8;
    const int nch = (cl[tid] + 255) >> 8;
    for (int k = 0; k < nch; ++k) chunk_class[start + k] = tid;
  }
  for (int k = totChunks + tid; k < fillTo; k += 256) chunk_class[k] = -1;
}

__global__ __launch_bounds__(256) void scatter_k(const int* __restrict__ ind,
    const int* __restrict__ blkbase, int* __restrict__ order, int shift, int C)
{
  __shared__ int lcur[256], lbase[256];
  const int tid = threadIdx.x, b = blockIdx.x;
  lcur[tid] = 0;
  if (tid < C) lbase[tid] = blkbase[b * C + tid];
  __syncthreads();
  const int base = b * BCHUNK;
#pragma unroll
  for (int r = 0; r < BCHUNK; r += 256) {
    const int p = base + r + tid;
    const int c = ind[p] >> shift;
    const int rank = atomicAdd(&lcur[c], 1);
    order[lbase[c] + rank] = p;
  }
}

// ---------------------------------------------------------------------------
extern "C" void kernel_launch(void* const* d_in, const int* in_sizes, int n_in,
                              void* d_out, int out_size, void* d_ws, size_t ws_size,
                              hipStream_t stream)
{
  const int N = N_PIX;
  const float* x_in  = (const float*)d_in[0];
  const float* bb1_w = (const float*)d_in[1];  const float* bb1_b = (const float*)d_in[2];
  const float* bb2_w = (const float*)d_in[3];  const float* bb2_b = (const float*)d_in[4];
  const float* bb3_w = (const float*)d_in[5];  const float* bb3_b = (const float*)d_in[6];
  const float* msk1_w= (const float*)d_in[7];  const float* msk1_b= (const float*)d_in[8];
  const float* msk2_w= (const float*)d_in[9];  const float* msk2_b= (const float*)d_in[10];
  const float* msk3_w= (const float*)d_in[11]; const float* msk3_b= (const float*)d_in[12];
  const float* c10_w = (const float*)d_in[13]; const float* c10_b = (const float*)d_in[14];
  const float* c20_w = (const float*)d_in[15]; const float* c20_b = (const float*)d_in[16];
  const float* c30_w = (const float*)d_in[17]; const float* c30_b = (const float*)d_in[18];
  const float* c11_W = (const float*)d_in[19]; const float* c11_b = (const float*)d_in[20];
  const float* c21_W = (const float*)d_in[21]; const float* c21_b = (const float*)d_in[22];
  const float* c31_W = (const float*)d_in[23]; const float* c31_b = (const float*)d_in[24];
  const float* c12_W = (const float*)d_in[25]; const float* c12_b = (const float*)d_in[26];
  const float* c22_W = (const float*)d_in[27]; const float* c22_b = (const float*)d_in[28];
  const float* c32_W = (const float*)d_in[29]; const float* c32_b = (const float*)d_in[30];
  const float* r1_w  = (const float*)d_in[31]; const float* r1_b  = (const float*)d_in[32];
  const float* r2_W  = (const float*)d_in[33]; const float* r2_b  = (const float*)d_in[34];
  const float* r3_W  = (const float*)d_in[35]; const float* r3_b  = (const float*)d_in[36];

  // ws layout (fp32/i32), ~19.6 MB total
  float* act     = (float*)d_ws;                    // N*128
  int*   inds1   = (int*)(act + (size_t)N * 128);   // N
  int*   inds12  = inds1 + N;                       // N
  int*   inds123 = inds12 + N;                      // N
  int*   counts  = inds123 + N;                     // 256
  int*   offs    = counts + 256;                    // 256
  int*   chunk_cls = offs + 256;                    // CHUNK_CAP
  int*   order     = chunk_cls + CHUNK_CAP;         // ORDER_CAP
  int*   blkcnt    = order + ORDER_CAP;             // NB*256
  int*   blkbase   = blkcnt + NB*256;               // NB*256

  float* out_reg  = (float*)d_out;       // [N] regression output (return slot 0)
  float* out_mask = out_reg + N;         // [N] mask output (return slot 1)

  const dim3 B(256);
  const int gPix64  = N / 64;    // 560
  const int gPix256 = N / 256;   // 140

  // --- backbone (in-place act) ---
  dense128_k<1><<<gPix64, B, 0, stream>>>(x_in, bb1_w, bb1_b, act, N);
  dense128_k<0><<<gPix64, B, 0, stream>>>(act,  bb2_w, bb2_b, act, N);
  dense128_k<0><<<gPix64, B, 0, stream>>>(act,  bb3_w, bb3_b, act, N);  // act = feat

  // --- mask head (x_in only) ---
  mask_k<<<gPix256, B, 0, stream>>>(x_in, msk1_w, msk1_b, msk2_w, msk2_b,
                                    msk3_w, msk3_b, out_mask, N);

  // --- stage 1: dense classifier -> inds1 ---
  stage1_k<<<gPix256, B, 0, stream>>>(act, c10_w, c10_b, c20_w, c20_b,
                                      c30_w, c30_b, inds1, N);

  // --- stage 2: bin by inds1 (16 cls), CondMul -> inds12 ---
  hist_k<<<NB, B, 0, stream>>>(inds1, blkcnt, 0, 16);
  scan_k<<<1, B, 0, stream>>>(blkcnt, blkbase, offs, counts, chunk_cls, 16, G_S2);
  scatter_k<<<NB, B, 0, stream>>>(inds1, blkbase, order, 0, 16);
  stage23_k<<<G_S2, B, 0, stream>>>(act, c11_W, c11_b, c21_W, c21_b, c31_W, c31_b,
                                    chunk_cls, order, offs, counts, inds12, 255);

  // --- stage 3: bin by inds12 (256 cls), CondMul -> inds123 ---
  hist_k<<<NB, B, 0, stream>>>(inds12, blkcnt, 0, 256);
  scan_k<<<1, B, 0, stream>>>(blkcnt, blkbase, offs, counts, chunk_cls, 256, G_S3);
  scatter_k<<<NB, B, 0, stream>>>(inds12, blkbase, order, 0, 256);
  stage23_k<<<G_S3, B, 0, stream>>>(act, c12_W, c12_b, c22_W, c22_b, c32_W, c32_b,
                                    chunk_cls, order, offs, counts, inds123, 4095);

  // --- regression input: xr = lrelu(r1 @ x_in), overwrites act (feat dead) ---
  dense128_k<1><<<gPix64, B, 0, stream>>>(x_in, r1_w, r1_b, act, N);

  // --- bin by super-class (inds123 >> 9, 8 cls), r2 + gathered r3 -> out ---
  hist_k<<<NB, B, 0, stream>>>(inds123, blkcnt, 9, 8);
  scan_k<<<1, B, 0, stream>>>(blkcnt, blkbase, offs, counts, chunk_cls, 8, G_RG);
  scatter_k<<<NB, B, 0, stream>>>(inds123, blkbase, order, 9, 8);
  reg_k<<<G_RG, B, 0, stream>>>(act, r2_W, r2_b, r3_W, r3_b,
                                chunk_cls, order, offs, counts, inds123, out_reg);
}